// Round 9
// baseline (247.529 us; speedup 1.0000x reference)
//
#include <hip/hip_runtime.h>

// Depth-4 path signature, D=6 — SINGLE fused launch, sized to FIT ~60 VGPRs.
// R7/R8 lesson: the allocator pins this kernel at 60 VGPRs regardless of
// __launch_bounds__; any design with >~55 live floats spills to scratch and
// serializes (200us at VALUBusy 4%). So: no prefetch register sets, one
// G-temp at a time in Phase A, B-operands loaded at use in combines.
//
// Phase A: wave w computes chunk 4b+w (36-lane Chen recursion, CL steps) on
//   LDS-precomputed zero-padded increment rows (v=0 is an exact identity).
// Phase B: 216-lane combine of the 4 wave-states from LDS.
// Phase C: 3-level last-arriver election tree (GSZ=16): NB -> ceil(NB/16)
//   -> ceil(./16) -> 1; each combiner does <=15 serial products, loading B
//   directly from global (L2-warm).
//
// Internal state layout (floats): L4 [0,1296) L3 [1296,1512) L2 [1512,1548)
// L1 [1548,1554). Output uses reference layout L1|L2|L3|L4.
#define SIGSZ 1554
#define PSTRIDE 1600
#define OFF4 0
#define OFF3 1296
#define OFF2 1512
#define OFF1 1548
#define SSTRIDE 1560      // LDS state stride
#define MAXCL 32
#define NBMAX 2048
#define GSZ 16
#define CTR2OFF 128
#define CTR3OFF 140

#define REP6(M) M(0) M(1) M(2) M(3) M(4) M(5)
#define REP6B(M, k) M(k, 0) M(k, 1) M(k, 2) M(k, 3) M(k, 4) M(k, 5)
#define REP36(M) \
  REP6B(M, 0) REP6B(M, 1) REP6B(M, 2) REP6B(M, 3) REP6B(M, 4) REP6B(M, 5)

__device__ __forceinline__ float sel6(int idx, float a0, float a1, float a2,
                                      float a3, float a4, float a5) {
  float r = a0;
  r = (idx == 1) ? a1 : r;
  r = (idx == 2) ? a2 : r;
  r = (idx == 3) ? a3 : r;
  r = (idx == 4) ? a4 : r;
  r = (idx == 5) ? a5 : r;
  return r;
}

// ---- combine: C = A (x) B with old-A on RHS; B loaded AT USE from bp ----
//   C4[ijk,l] = A4 + B4[ijk,l] + A1[i]B3[jk,l] + A2[ij]B2[k,l] + A3[ijk]B1[l]
//   C3[ijk]   = A3 + B3[ijk] + A1[i]B2[jk] + A2[ij]B1[k]
//   C2[ij]    = A2 + B2[ij] + A1[i]B1[j] ;  C1 = A1 + B1
#define PRODG(bp) {                                                    \
  const float2* q4 = (const float2*)((bp) + oB4);                      \
  const float2 u0 = q4[0], u1 = q4[1], u2 = q4[2];                     \
  const float2* q3 = (const float2*)((bp) + oB3r);                     \
  const float2 w0 = q3[0], w1 = q3[1], w2 = q3[2];                     \
  const float2* q2 = (const float2*)((bp) + oB2r);                     \
  const float2 y0 = q2[0], y1 = q2[1], y2 = q2[2];                     \
  const float2* q1 = (const float2*)((bp) + OFF1);                     \
  const float2 z0 = q1[0], z1 = q1[1], z2 = q1[2];                     \
  const float b2ij = (bp)[oB2ij], b2jk = (bp)[oB2jk];                  \
  const float b3ijk = (bp)[oB3ijk];                                    \
  const float b1k = (bp)[oB1k], b1j = (bp)[oB1j], b1i = (bp)[oB1i];    \
  a4_0 = fmaf(a3, z0.x, fmaf(a2, y0.x, fmaf(a1i, w0.x, a4_0 + u0.x))); \
  a4_1 = fmaf(a3, z0.y, fmaf(a2, y0.y, fmaf(a1i, w0.y, a4_1 + u0.y))); \
  a4_2 = fmaf(a3, z1.x, fmaf(a2, y1.x, fmaf(a1i, w1.x, a4_2 + u1.x))); \
  a4_3 = fmaf(a3, z1.y, fmaf(a2, y1.y, fmaf(a1i, w1.y, a4_3 + u1.y))); \
  a4_4 = fmaf(a3, z2.x, fmaf(a2, y2.x, fmaf(a1i, w2.x, a4_4 + u2.x))); \
  a4_5 = fmaf(a3, z2.y, fmaf(a2, y2.y, fmaf(a1i, w2.y, a4_5 + u2.y))); \
  a3 = fmaf(a2, b1k, fmaf(a1i, b2jk, a3 + b3ijk));                     \
  a2 = fmaf(a1i, b1j, a2 + b2ij);                                      \
  a1i += b1i;                                                          \
  a1_0 += z0.x; a1_1 += z0.y; a1_2 += z1.x;                            \
  a1_3 += z1.y; a1_4 += z2.x; a1_5 += z2.y;                            \
}

#define INITA(bp) {                                                    \
  const float2* q4 = (const float2*)((bp) + oB4);                      \
  const float2 u0 = q4[0], u1 = q4[1], u2 = q4[2];                     \
  a4_0 = u0.x; a4_1 = u0.y; a4_2 = u1.x;                               \
  a4_3 = u1.y; a4_4 = u2.x; a4_5 = u2.y;                               \
  a3 = (bp)[oB3ijk]; a2 = (bp)[oB2ij];                                 \
  const float2* q1 = (const float2*)((bp) + OFF1);                     \
  const float2 z0 = q1[0], z1 = q1[1], z2 = q1[2];                     \
  a1_0 = z0.x; a1_1 = z0.y; a1_2 = z1.x;                               \
  a1_3 = z1.y; a1_4 = z2.x; a1_5 = z2.y;                               \
  a1i = (bp)[oB1i];                                                    \
}

// write a-regs as an internal-layout state (216-lane)
#define STORE_STATE(dst) {                                             \
  if (act2) {                                                          \
    float2* o2 = (float2*)((dst) + oB4);                               \
    float2 wv_;                                                        \
    wv_.x = a4_0; wv_.y = a4_1; o2[0] = wv_;                           \
    wv_.x = a4_2; wv_.y = a4_3; o2[1] = wv_;                           \
    wv_.x = a4_4; wv_.y = a4_5; o2[2] = wv_;                           \
    (dst)[oB3ijk] = a3;                                                \
    if (k2 == 0) (dst)[oB2ij] = a2;                                    \
  }                                                                    \
  if (tid < 6) (dst)[OFF1 + tid] = sel6(tid, a1_0, a1_1, a1_2,         \
                                        a1_3, a1_4, a1_5);             \
}

__global__ __launch_bounds__(256, 1) void sig_fused(
    const float* __restrict__ x, float* __restrict__ ws1,
    float* __restrict__ ws2, float* __restrict__ ws3,
    int* __restrict__ ctr, float* __restrict__ out,
    int n_inc, int CL, int NB, int NL1, int NL2) {
  __shared__ __align__(16) float xls[(4 * MAXCL + 1) * 6];
  __shared__ __align__(16) float vls[4 * MAXCL * 6];
  __shared__ __align__(16) float Sb[4 * SSTRIDE];
  __shared__ int flag;

  const int b = blockIdx.x;
  const int tid = threadIdx.x;
  const int w = tid >> 6;
  const int lane = tid & 63;

  // ---- stage x rows, then zero-padded increment rows, into LDS ----
  const int t0b = b * 4 * CL;
  const int xtot = (4 * CL + 1) * 6;
  const int xlim = (n_inc + 1) * 6 - t0b * 6;   // valid staged floats
  for (int idx = tid; idx < xtot; idx += 256)
    xls[idx] = (idx < xlim) ? x[(size_t)t0b * 6 + idx] : 0.f;
  __syncthreads();
  const int remi = n_inc - t0b;
  const int vlim = (remi > 0) ? remi * 6 : 0;
  const int vtot = 4 * CL * 6;
  for (int idx = tid; idx < vtot; idx += 256)
    vls[idx] = (idx < vlim) ? (xls[idx + 6] - xls[idx]) : 0.f;
  __syncthreads();

  // ---- Phase A: per-wave 36-lane Chen recursion over CL increments ----
  // lane pc<36 owns (i,j); S4[ij..](36) S3[ij.](6) S2,S1 in named scalars.
  //   S4[ijkl] += G*v_l, G  = (vi*vj/24 + S1i*vj/6 + S2/2)*vk + S3[k]
  //   S3[k]    += G2*vk, G2 =  vi*vj/6  + S1i*vj/2 + S2
  //   S2 += (vi/2+S1i)*vj ; S1i += vi     (old values on RHS)
  // Only ONE G live at a time (k-fused loop) to stay under the VGPR budget.
  const int pc = (lane < 36) ? lane : 35;
  const int i_ = pc / 6, j_ = pc % 6;

#define DECL_S4(k, l) float s4_##k##_##l = 0.f;
  REP36(DECL_S4)
#undef DECL_S4
#define DECL_S3(k) float s3_##k = 0.f;
  REP6(DECL_S3)
#undef DECL_S3
  float s1i = 0.f, s2 = 0.f;

  const float* vp = vls + w * CL * 6;
#pragma unroll 2
  for (int r = 0; r < CL; ++r) {
    const float2* q = (const float2*)(vp + r * 6);
    const float2 qa = q[0], qb = q[1], qc = q[2];
    const float v0 = qa.x, v1 = qa.y, v2 = qb.x;
    const float v3 = qb.y, v4 = qc.x, v5 = qc.y;
    const float vi = vp[r * 6 + i_];
    const float vj = vp[r * 6 + j_];

    const float aa = vi * vj;
    const float sv = s1i * vj;
    const float G2  = fmaf(aa, 1.f / 6.f,  fmaf(sv, 0.5f,      s2));
    const float in4 = fmaf(aa, 1.f / 24.f, fmaf(sv, 1.f / 6.f, s2 * 0.5f));
#define STEPK(k) {                                      \
    const float G = fmaf(in4, v##k, s3_##k);            \
    s3_##k = fmaf(G2, v##k, s3_##k);                    \
    s4_##k##_0 = fmaf(G, v0, s4_##k##_0);               \
    s4_##k##_1 = fmaf(G, v1, s4_##k##_1);               \
    s4_##k##_2 = fmaf(G, v2, s4_##k##_2);               \
    s4_##k##_3 = fmaf(G, v3, s4_##k##_3);               \
    s4_##k##_4 = fmaf(G, v4, s4_##k##_4);               \
    s4_##k##_5 = fmaf(G, v5, s4_##k##_5);               \
  }
    REP6(STEPK)
#undef STEPK
    s2 = fmaf(fmaf(vi, 0.5f, s1i), vj, s2);
    s1i += vi;
  }

  // ---- write wave state into LDS (internal layout, stride SSTRIDE) ----
  {
    float* st = Sb + w * SSTRIDE;
    if (lane < 36) {
      float4* o4 = (float4*)(st + OFF4 + pc * 36);
      float4 wv;
      wv.x = s4_0_0; wv.y = s4_0_1; wv.z = s4_0_2; wv.w = s4_0_3; o4[0] = wv;
      wv.x = s4_0_4; wv.y = s4_0_5; wv.z = s4_1_0; wv.w = s4_1_1; o4[1] = wv;
      wv.x = s4_1_2; wv.y = s4_1_3; wv.z = s4_1_4; wv.w = s4_1_5; o4[2] = wv;
      wv.x = s4_2_0; wv.y = s4_2_1; wv.z = s4_2_2; wv.w = s4_2_3; o4[3] = wv;
      wv.x = s4_2_4; wv.y = s4_2_5; wv.z = s4_3_0; wv.w = s4_3_1; o4[4] = wv;
      wv.x = s4_3_2; wv.y = s4_3_3; wv.z = s4_3_4; wv.w = s4_3_5; o4[5] = wv;
      wv.x = s4_4_0; wv.y = s4_4_1; wv.z = s4_4_2; wv.w = s4_4_3; o4[6] = wv;
      wv.x = s4_4_4; wv.y = s4_4_5; wv.z = s4_5_0; wv.w = s4_5_1; o4[7] = wv;
      wv.x = s4_5_2; wv.y = s4_5_3; wv.z = s4_5_4; wv.w = s4_5_5; o4[8] = wv;
#define ST3(k) st[OFF3 + pc * 6 + k] = s3_##k;
      REP6(ST3)
#undef ST3
      st[OFF2 + pc] = s2;
      if (j_ == 0) st[OFF1 + i_] = s1i;
    }
  }
  __syncthreads();

  // ---- Phase B: 216-lane combine of the 4 wave states (B from LDS) ----
  const int tc = (tid < 216) ? tid : 215;
  const bool act2 = (tid < 216);
  const int k2 = tc % 6;
  const int ij2 = tc / 6;
  const int j2 = ij2 % 6;
  const int i2 = ij2 / 6;
  const int oB4 = OFF4 + tc * 6;
  const int oB3r = OFF3 + (j2 * 6 + k2) * 6;
  const int oB2r = OFF2 + k2 * 6;
  const int oB2ij = OFF2 + ij2;
  const int oB2jk = OFF2 + j2 * 6 + k2;
  const int oB3ijk = OFF3 + tc;
  const int oB1k = OFF1 + k2;
  const int oB1j = OFF1 + j2;
  const int oB1i = OFF1 + i2;

  float a4_0, a4_1, a4_2, a4_3, a4_4, a4_5, a3, a2;
  float a1_0, a1_1, a1_2, a1_3, a1_4, a1_5, a1i;
  INITA((const float*)Sb)
  PRODG((const float*)(Sb + 1 * SSTRIDE))
  PRODG((const float*)(Sb + 2 * SSTRIDE))
  PRODG((const float*)(Sb + 3 * SSTRIDE))

  STORE_STATE(ws1 + (size_t)b * PSTRIDE)
  __threadfence();
  __syncthreads();

  // ---- Phase C level 1: groups of GSZ blocks ----
  {
    const int g = b / GSZ;
    const int gbase = g * GSZ;
    int gcnt = NB - gbase; if (gcnt > GSZ) gcnt = GSZ;
    if (tid == 0) {
      const int ret = atomicAdd(&ctr[g], 1);
      flag = (ret == gcnt - 1) ? 1 : 0;
    }
    __syncthreads();
    if (!flag) return;
    __threadfence();
    const float* base = ws1 + (size_t)gbase * PSTRIDE;
    INITA(base)
    for (int s_ = 1; s_ < gcnt; ++s_) PRODG(base + (size_t)s_ * PSTRIDE)
    STORE_STATE(ws2 + (size_t)g * PSTRIDE)
    __threadfence();
    __syncthreads();

    // ---- level 2 ----
    const int g2 = g / GSZ;
    const int g2base = g2 * GSZ;
    int g2cnt = NL1 - g2base; if (g2cnt > GSZ) g2cnt = GSZ;
    if (tid == 0) {
      const int ret = atomicAdd(&ctr[CTR2OFF + g2], 1);
      flag = (ret == g2cnt - 1) ? 1 : 0;
    }
    __syncthreads();
    if (!flag) return;
    __threadfence();
    const float* base2 = ws2 + (size_t)g2base * PSTRIDE;
    INITA(base2)
    for (int s_ = 1; s_ < g2cnt; ++s_) PRODG(base2 + (size_t)s_ * PSTRIDE)
    STORE_STATE(ws3 + (size_t)g2 * PSTRIDE)
    __threadfence();
    __syncthreads();

    // ---- level 3 (final) ----
    if (tid == 0) {
      const int ret = atomicAdd(&ctr[CTR3OFF], 1);
      flag = (ret == NL2 - 1) ? 1 : 0;
    }
    __syncthreads();
    if (!flag) return;
    __threadfence();
    INITA((const float*)ws3)
    for (int s_ = 1; s_ < NL2; ++s_) PRODG(ws3 + (size_t)s_ * PSTRIDE)

    // reference layout out: L1[0,6) L2[6,42) L3[42,258) L4[258,1554)
    if (act2) {
      float2* o2 = (float2*)(out + 258 + tc * 6);
      float2 wv;
      wv.x = a4_0; wv.y = a4_1; o2[0] = wv;
      wv.x = a4_2; wv.y = a4_3; o2[1] = wv;
      wv.x = a4_4; wv.y = a4_5; o2[2] = wv;
      out[42 + tc] = a3;
      if (k2 == 0) out[6 + ij2] = a2;
    }
    if (tid < 6) out[tid] = sel6(tid, a1_0, a1_1, a1_2, a1_3, a1_4, a1_5);
  }
}

extern "C" void kernel_launch(void* const* d_in, const int* in_sizes, int n_in,
                              void* d_out, int out_size, void* d_ws, size_t ws_size,
                              hipStream_t stream) {
  const float* x = (const float*)d_in[0];
  const int Lrows = in_sizes[0] / 6;
  const int n_inc = Lrows - 1;

  int CL = (n_inc + 4096 - 1) / 4096;          // target ~1024 blocks
  if (CL < 1) CL = 1;
  if (CL > MAXCL) CL = MAXCL;
  int NB = (n_inc + 4 * CL - 1) / (4 * CL);
  if (NB > NBMAX) NB = NBMAX;                  // (L fixed at 1e5: never hit)
  const int NL1 = (NB + GSZ - 1) / GSZ;        // <= 128
  const int NL2 = (NL1 + GSZ - 1) / GSZ;       // <= 8

  float* ws1 = (float*)d_ws;
  float* ws2 = ws1 + (size_t)NBMAX * PSTRIDE;
  float* ws3 = ws2 + (size_t)128 * PSTRIDE;
  int* ctr = (int*)(ws3 + (size_t)16 * PSTRIDE);

  hipMemsetAsync(ctr, 0, (size_t)(CTR3OFF + 1) * sizeof(int), stream);
  sig_fused<<<NB, 256, 0, stream>>>(x, ws1, ws2, ws3, ctr, (float*)d_out,
                                    n_inc, CL, NB, NL1, NL2);
}

// Round 10
// 95.719 us; speedup vs baseline: 2.5860x; 2.5860x over previous
//
#include <hip/hip_runtime.h>

// Depth-4 path signature, D=6. Three launches, NO device-scope fences:
// R9's fused single-launch (threadfence + election per block) ran 236us at
// VALUBusy 3.6% -- agent-scope fences on non-coherent per-XCD L2s force
// writeback/invalidate storms. Kernel boundaries give coherence for free.
//
// k1: 1000 blocks x 256 thr; wave w computes chunk 4b+w (36-lane Chen
//     recursion, CL steps) on LDS-precomputed zero-padded increment rows
//     (v=0 is an exact identity step); then 216-lane intra-block combine
//     of the 4 wave states -> ws1[b].  (R9 Phase A+B: VGPR 48, no spills,
//     FETCH/WRITE at algorithmic minimum.)
// k2: 32 blocks fold ws1[1000] -> ws2[32] (<=32 serial products each,
//     B-operands loaded at use, L2/LLC-warm).
// k3: 1 block folds ws2[32] -> out (reference layout).
//
// Internal state layout (floats): L4 [0,1296) L3 [1296,1512) L2 [1512,1548)
// L1 [1548,1554). Output layout: L1[0,6) L2[6,42) L3[42,258) L4[258,1554).
#define SIGSZ 1554
#define PSTRIDE 1600
#define OFF4 0
#define OFF3 1296
#define OFF2 1512
#define OFF1 1548
#define SSTRIDE 1560      // LDS state stride
#define MAXCL 32
#define NBMAX 2048
#define G2SZ 32

#define REP6(M) M(0) M(1) M(2) M(3) M(4) M(5)
#define REP6B(M, k) M(k, 0) M(k, 1) M(k, 2) M(k, 3) M(k, 4) M(k, 5)
#define REP36(M) \
  REP6B(M, 0) REP6B(M, 1) REP6B(M, 2) REP6B(M, 3) REP6B(M, 4) REP6B(M, 5)

__device__ __forceinline__ float sel6(int idx, float a0, float a1, float a2,
                                      float a3, float a4, float a5) {
  float r = a0;
  r = (idx == 1) ? a1 : r;
  r = (idx == 2) ? a2 : r;
  r = (idx == 3) ? a3 : r;
  r = (idx == 4) ? a4 : r;
  r = (idx == 5) ? a5 : r;
  return r;
}

// lane tc<216 owns (i,j,k); offsets oB* are loop-invariant per lane.
#define DECL_OFFS(tc)                         \
  const int k2c = (tc) % 6;                   \
  const int ij2 = (tc) / 6;                   \
  const int j2 = ij2 % 6;                     \
  const int i2 = ij2 / 6;                     \
  const int oB4 = OFF4 + (tc) * 6;            \
  const int oB3r = OFF3 + (j2 * 6 + k2c) * 6; \
  const int oB2r = OFF2 + k2c * 6;            \
  const int oB2ij = OFF2 + ij2;               \
  const int oB2jk = OFF2 + j2 * 6 + k2c;      \
  const int oB3ijk = OFF3 + (tc);             \
  const int oB1k = OFF1 + k2c;                \
  const int oB1j = OFF1 + j2;                 \
  const int oB1i = OFF1 + i2;

// ---- combine: C = A (x) B with old-A on RHS; B loaded AT USE from bp ----
#define PRODG(bp) {                                                    \
  const float2* q4 = (const float2*)((bp) + oB4);                      \
  const float2 u0 = q4[0], u1 = q4[1], u2 = q4[2];                     \
  const float2* q3 = (const float2*)((bp) + oB3r);                     \
  const float2 w0 = q3[0], w1 = q3[1], w2 = q3[2];                     \
  const float2* q2 = (const float2*)((bp) + oB2r);                     \
  const float2 y0 = q2[0], y1 = q2[1], y2 = q2[2];                     \
  const float2* q1 = (const float2*)((bp) + OFF1);                     \
  const float2 z0 = q1[0], z1 = q1[1], z2 = q1[2];                     \
  const float b2ij = (bp)[oB2ij], b2jk = (bp)[oB2jk];                  \
  const float b3ijk = (bp)[oB3ijk];                                    \
  const float b1k = (bp)[oB1k], b1j = (bp)[oB1j], b1i = (bp)[oB1i];    \
  a4_0 = fmaf(a3, z0.x, fmaf(a2, y0.x, fmaf(a1i, w0.x, a4_0 + u0.x))); \
  a4_1 = fmaf(a3, z0.y, fmaf(a2, y0.y, fmaf(a1i, w0.y, a4_1 + u0.y))); \
  a4_2 = fmaf(a3, z1.x, fmaf(a2, y1.x, fmaf(a1i, w1.x, a4_2 + u1.x))); \
  a4_3 = fmaf(a3, z1.y, fmaf(a2, y1.y, fmaf(a1i, w1.y, a4_3 + u1.y))); \
  a4_4 = fmaf(a3, z2.x, fmaf(a2, y2.x, fmaf(a1i, w2.x, a4_4 + u2.x))); \
  a4_5 = fmaf(a3, z2.y, fmaf(a2, y2.y, fmaf(a1i, w2.y, a4_5 + u2.y))); \
  a3 = fmaf(a2, b1k, fmaf(a1i, b2jk, a3 + b3ijk));                     \
  a2 = fmaf(a1i, b1j, a2 + b2ij);                                      \
  a1i += b1i;                                                          \
  a1_0 += z0.x; a1_1 += z0.y; a1_2 += z1.x;                            \
  a1_3 += z1.y; a1_4 += z2.x; a1_5 += z2.y;                            \
}

#define DECL_A \
  float a4_0, a4_1, a4_2, a4_3, a4_4, a4_5, a3, a2; \
  float a1_0, a1_1, a1_2, a1_3, a1_4, a1_5, a1i;

#define INITA(bp) {                                                    \
  const float2* q4 = (const float2*)((bp) + oB4);                      \
  const float2 u0 = q4[0], u1 = q4[1], u2 = q4[2];                     \
  a4_0 = u0.x; a4_1 = u0.y; a4_2 = u1.x;                               \
  a4_3 = u1.y; a4_4 = u2.x; a4_5 = u2.y;                               \
  a3 = (bp)[oB3ijk]; a2 = (bp)[oB2ij];                                 \
  const float2* q1 = (const float2*)((bp) + OFF1);                     \
  const float2 z0 = q1[0], z1 = q1[1], z2 = q1[2];                     \
  a1_0 = z0.x; a1_1 = z0.y; a1_2 = z1.x;                               \
  a1_3 = z1.y; a1_4 = z2.x; a1_5 = z2.y;                               \
  a1i = (bp)[oB1i];                                                    \
}

// write a-regs as an internal-layout state (216-lane)
#define STORE_STATE(dst) {                                             \
  if (act2) {                                                          \
    float2* o2 = (float2*)((dst) + oB4);                               \
    float2 wv_;                                                        \
    wv_.x = a4_0; wv_.y = a4_1; o2[0] = wv_;                           \
    wv_.x = a4_2; wv_.y = a4_3; o2[1] = wv_;                           \
    wv_.x = a4_4; wv_.y = a4_5; o2[2] = wv_;                           \
    (dst)[oB3ijk] = a3;                                                \
    if (k2c == 0) (dst)[oB2ij] = a2;                                   \
  }                                                                    \
  if (tid < 6) (dst)[OFF1 + tid] = sel6(tid, a1_0, a1_1, a1_2,         \
                                        a1_3, a1_4, a1_5);             \
}

// ---------------------------------------------------------------------------
// k1: per-wave Chen recursion + intra-block combine of 4 wave states.
// ---------------------------------------------------------------------------
__global__ __launch_bounds__(256, 1) void sig_part1(
    const float* __restrict__ x, float* __restrict__ ws1,
    int n_inc, int CL) {
  __shared__ __align__(16) float xls[(4 * MAXCL + 1) * 6];
  __shared__ __align__(16) float vls[4 * MAXCL * 6];
  __shared__ __align__(16) float Sb[4 * SSTRIDE];

  const int b = blockIdx.x;
  const int tid = threadIdx.x;
  const int w = tid >> 6;
  const int lane = tid & 63;

  // ---- stage x rows, then zero-padded increment rows, into LDS ----
  const int t0b = b * 4 * CL;
  const int xtot = (4 * CL + 1) * 6;
  const int xlim = (n_inc + 1) * 6 - t0b * 6;
  for (int idx = tid; idx < xtot; idx += 256)
    xls[idx] = (idx < xlim) ? x[(size_t)t0b * 6 + idx] : 0.f;
  __syncthreads();
  const int remi = n_inc - t0b;
  const int vlim = (remi > 0) ? remi * 6 : 0;
  const int vtot = 4 * CL * 6;
  for (int idx = tid; idx < vtot; idx += 256)
    vls[idx] = (idx < vlim) ? (xls[idx + 6] - xls[idx]) : 0.f;
  __syncthreads();

  // ---- Phase A: 36-lane Chen recursion over CL increments ----
  //   S4[ijkl] += G*v_l, G  = (vi*vj/24 + S1i*vj/6 + S2/2)*vk + S3[k]
  //   S3[k]    += G2*vk, G2 =  vi*vj/6  + S1i*vj/2 + S2
  //   S2 += (vi/2+S1i)*vj ; S1i += vi     (old values on RHS)
  const int pc = (lane < 36) ? lane : 35;
  const int i_ = pc / 6, j_ = pc % 6;

#define DECL_S4(k, l) float s4_##k##_##l = 0.f;
  REP36(DECL_S4)
#undef DECL_S4
#define DECL_S3(k) float s3_##k = 0.f;
  REP6(DECL_S3)
#undef DECL_S3
  float s1i = 0.f, s2 = 0.f;

  const float* vp = vls + w * CL * 6;
#pragma unroll 2
  for (int r = 0; r < CL; ++r) {
    const float2* q = (const float2*)(vp + r * 6);
    const float2 qa = q[0], qb = q[1], qc = q[2];
    const float v0 = qa.x, v1 = qa.y, v2 = qb.x;
    const float v3 = qb.y, v4 = qc.x, v5 = qc.y;
    const float vi = vp[r * 6 + i_];
    const float vj = vp[r * 6 + j_];

    const float aa = vi * vj;
    const float sv = s1i * vj;
    const float G2  = fmaf(aa, 1.f / 6.f,  fmaf(sv, 0.5f,      s2));
    const float in4 = fmaf(aa, 1.f / 24.f, fmaf(sv, 1.f / 6.f, s2 * 0.5f));
#define STEPK(k) {                                      \
    const float G = fmaf(in4, v##k, s3_##k);            \
    s3_##k = fmaf(G2, v##k, s3_##k);                    \
    s4_##k##_0 = fmaf(G, v0, s4_##k##_0);               \
    s4_##k##_1 = fmaf(G, v1, s4_##k##_1);               \
    s4_##k##_2 = fmaf(G, v2, s4_##k##_2);               \
    s4_##k##_3 = fmaf(G, v3, s4_##k##_3);               \
    s4_##k##_4 = fmaf(G, v4, s4_##k##_4);               \
    s4_##k##_5 = fmaf(G, v5, s4_##k##_5);               \
  }
    REP6(STEPK)
#undef STEPK
    s2 = fmaf(fmaf(vi, 0.5f, s1i), vj, s2);
    s1i += vi;
  }

  // ---- wave state -> LDS (internal layout) ----
  {
    float* st = Sb + w * SSTRIDE;
    if (lane < 36) {
      float4* o4 = (float4*)(st + OFF4 + pc * 36);
      float4 wv;
      wv.x = s4_0_0; wv.y = s4_0_1; wv.z = s4_0_2; wv.w = s4_0_3; o4[0] = wv;
      wv.x = s4_0_4; wv.y = s4_0_5; wv.z = s4_1_0; wv.w = s4_1_1; o4[1] = wv;
      wv.x = s4_1_2; wv.y = s4_1_3; wv.z = s4_1_4; wv.w = s4_1_5; o4[2] = wv;
      wv.x = s4_2_0; wv.y = s4_2_1; wv.z = s4_2_2; wv.w = s4_2_3; o4[3] = wv;
      wv.x = s4_2_4; wv.y = s4_2_5; wv.z = s4_3_0; wv.w = s4_3_1; o4[4] = wv;
      wv.x = s4_3_2; wv.y = s4_3_3; wv.z = s4_3_4; wv.w = s4_3_5; o4[5] = wv;
      wv.x = s4_4_0; wv.y = s4_4_1; wv.z = s4_4_2; wv.w = s4_4_3; o4[6] = wv;
      wv.x = s4_4_4; wv.y = s4_4_5; wv.z = s4_5_0; wv.w = s4_5_1; o4[7] = wv;
      wv.x = s4_5_2; wv.y = s4_5_3; wv.z = s4_5_4; wv.w = s4_5_5; o4[8] = wv;
#define ST3(k) st[OFF3 + pc * 6 + k] = s3_##k;
      REP6(ST3)
#undef ST3
      st[OFF2 + pc] = s2;
      if (j_ == 0) st[OFF1 + i_] = s1i;
    }
  }
  __syncthreads();

  // ---- Phase B: 216-lane combine of the 4 wave states (B from LDS) ----
  const int tc = (tid < 216) ? tid : 215;
  const bool act2 = (tid < 216);
  DECL_OFFS(tc)
  DECL_A
  INITA((const float*)Sb)
  PRODG((const float*)(Sb + 1 * SSTRIDE))
  PRODG((const float*)(Sb + 2 * SSTRIDE))
  PRODG((const float*)(Sb + 3 * SSTRIDE))
  STORE_STATE(ws1 + (size_t)b * PSTRIDE)
}

// ---------------------------------------------------------------------------
// k2: fold n states (stride PSTRIDE) in groups of `group` -> out states.
// ---------------------------------------------------------------------------
__global__ __launch_bounds__(256, 1) void sig_part2(
    const float* __restrict__ in, float* __restrict__ outst,
    int n, int group) {
  const int b = blockIdx.x;
  const int tid = threadIdx.x;
  const int base = b * group;
  int cnt = n - base; if (cnt > group) cnt = group;
  const int tc = (tid < 216) ? tid : 215;
  const bool act2 = (tid < 216);
  DECL_OFFS(tc)
  DECL_A
  const float* bp0 = in + (size_t)base * PSTRIDE;
  INITA(bp0)
  for (int s_ = 1; s_ < cnt; ++s_) PRODG(bp0 + (size_t)s_ * PSTRIDE)
  STORE_STATE(outst + (size_t)b * PSTRIDE)
}

// ---------------------------------------------------------------------------
// k3: fold n states -> final output in reference layout.
// ---------------------------------------------------------------------------
__global__ __launch_bounds__(256, 1) void sig_part3(
    const float* __restrict__ in, float* __restrict__ out, int n) {
  const int tid = threadIdx.x;
  const int tc = (tid < 216) ? tid : 215;
  const bool act2 = (tid < 216);
  DECL_OFFS(tc)
  DECL_A
  INITA(in)
  for (int s_ = 1; s_ < n; ++s_) PRODG(in + (size_t)s_ * PSTRIDE)

  if (act2) {
    float2* o2 = (float2*)(out + 258 + tc * 6);
    float2 wv;
    wv.x = a4_0; wv.y = a4_1; o2[0] = wv;
    wv.x = a4_2; wv.y = a4_3; o2[1] = wv;
    wv.x = a4_4; wv.y = a4_5; o2[2] = wv;
    out[42 + tc] = a3;
    if (k2c == 0) out[6 + ij2] = a2;
  }
  if (tid < 6) out[tid] = sel6(tid, a1_0, a1_1, a1_2, a1_3, a1_4, a1_5);
}

extern "C" void kernel_launch(void* const* d_in, const int* in_sizes, int n_in,
                              void* d_out, int out_size, void* d_ws, size_t ws_size,
                              hipStream_t stream) {
  const float* x = (const float*)d_in[0];
  const int Lrows = in_sizes[0] / 6;
  const int n_inc = Lrows - 1;

  int CL = (n_inc + 4000 - 1) / 4000;          // target ~1000 blocks
  if (CL < 1) CL = 1;
  if (CL > MAXCL) CL = MAXCL;
  int NB = (n_inc + 4 * CL - 1) / (4 * CL);
  if (NB > NBMAX) NB = NBMAX;                  // (L=1e5: CL=25, NB=1000)
  const int NL1 = (NB + G2SZ - 1) / G2SZ;      // <= 64

  float* ws1 = (float*)d_ws;
  float* ws2 = ws1 + (size_t)NBMAX * PSTRIDE;

  sig_part1<<<NB, 256, 0, stream>>>(x, ws1, n_inc, CL);
  sig_part2<<<NL1, 256, 0, stream>>>(ws1, ws2, NB, G2SZ);
  sig_part3<<<1, 256, 0, stream>>>(ws2, (float*)d_out, NL1);
}